// Round 5
// baseline (194.579 us; speedup 1.0000x reference)
//
#include <hip/hip_runtime.h>
#include <hip/hip_bf16.h>

typedef __attribute__((ext_vector_type(8))) short bf16x8;
typedef __attribute__((ext_vector_type(4))) float f32x4;

// ---------------- ws layout ----------------
// F    : bf16 [32768][672]            @ 0          (44,040,192 B)
// W2   : bf16 [768][672]              @ 44,040,192 (1,032,192 B)
// biasT: f32  [768]                   @ 45,072,384 (3,072 B)
// part : f32  [512]                   @ 45,075,456 (2,048 B)
// dmin : f32  [32]                    @ 45,077,504 (128 B)

__device__ __forceinline__ void async_copy16(const void* gsrc, void* ldst) {
    __builtin_amdgcn_global_load_lds(
        (const __attribute__((address_space(1))) void*)gsrc,
        (__attribute__((address_space(3))) void*)ldst,
        16, 0, 0);
}

__device__ __forceinline__ unsigned short f2bf(float f) {  // RNE, matches __float2bfloat16
    unsigned u = __float_as_uint(f);
    u += 0x7FFFu + ((u >> 16) & 1u);
    return (unsigned short)(u >> 16);
}

// -------- per-batch min (two stage) --------
__global__ __launch_bounds__(256) void min_partial_kernel(const float* __restrict__ x,
                                                          float* __restrict__ partial) {
    const int blk = blockIdx.x;           // 512 blocks: 32 batches x 16 chunks
    const int b = blk >> 4, c = blk & 15;
    const float4* p = (const float4*)(x + (size_t)b * 262144 + (size_t)c * 16384);
    float mn = 3.0e38f;
    for (int i = threadIdx.x; i < 4096; i += 256) {
        float4 v = p[i];
        mn = fminf(mn, fminf(fminf(v.x, v.y), fminf(v.z, v.w)));
    }
    #pragma unroll
    for (int off = 32; off > 0; off >>= 1)
        mn = fminf(mn, __shfl_down(mn, off));
    __shared__ float red[4];
    if ((threadIdx.x & 63) == 0) red[threadIdx.x >> 6] = mn;
    __syncthreads();
    if (threadIdx.x == 0)
        partial[blk] = fminf(fminf(red[0], red[1]), fminf(red[2], red[3]));
}

__global__ void min_final_kernel(const float* __restrict__ partial, float* __restrict__ dmin) {
    const int t = threadIdx.x;
    if (t < 32) {
        float mn = 3.0e38f;
        for (int i = 0; i < 16; ++i) mn = fminf(mn, partial[t * 16 + i]);
        dmin[t] = mn;
    }
}

// -------- weight repack: W2[e][k] bf16, k = [g16 dh|g16 mp|g8 dh|g8 mp|g4 dh|g4 mp] --------
__global__ __launch_bounds__(256) void prep_kernel(const float* __restrict__ w0, const float* __restrict__ b0,
                                                   const float* __restrict__ w1, const float* __restrict__ b1,
                                                   const float* __restrict__ w2, const float* __restrict__ b2,
                                                   __hip_bfloat16* __restrict__ W2, float* __restrict__ biasT) {
    const int idx = blockIdx.x * 256 + threadIdx.x;
    if (idx < 768 * 672) {
        const int e = idx / 672, k = idx - e * 672;
        float v;
        if (k < 512)      v = w0[e * 512 + k];          // (2,16,16) flat
        else if (k < 640) v = w1[e * 128 + (k - 512)];  // (2,8,8) flat
        else              v = w2[e * 32  + (k - 640)];  // (2,4,4) flat
        W2[idx] = __float2bfloat16(v);
    }
    if (idx < 768) biasT[idx] = b0[idx] + b1[idx] + b2[idx];
}

// -------- per-patch: one WAVE per patch (R2-proven pools + g16 fill);
// g8/g4 fills in registers. ALL __shfl run unconditionally on the uniform
// path (masked index), boundary handled by multiplicative 0/1 masks AFTER
// the shuffle; asm-pin prevents sinking shfls into divergent regions
// (ds_bpermute reads from EXEC-inactive lanes are undefined — R3/R4 bug). --------
__global__ __launch_bounds__(256) void patch_kernel(const float* __restrict__ x,
                                                    const float* __restrict__ dmin,
                                                    __hip_bfloat16* __restrict__ F,
                                                    float* __restrict__ maskout) {
    __shared__ float s_d0[4][256];
    __shared__ float s_m0[4][256];
    __shared__ float s_fd[4][256];

    const int t = threadIdx.x;
    const int pid0 = blockIdx.x * 4;          // 4 horizontally-adjacent patches
    const int b = pid0 >> 10;
    const int n0 = pid0 & 1023;
    const int gi = n0 >> 5, gj0 = n0 & 31;
    const float thr = dmin[b] + 1e-6f;

    // coalesced cooperative load: 16 rows x 64 cols (4 patches)
    {
        const int pr = t >> 4, ck = t & 15;
        const float4 v = *(const float4*)(x + ((size_t)(b * 512 + gi * 16 + pr)) * 512 + gj0 * 16 + ck * 4);
        const int p = ck >> 2;
        const int ci = pr * 16 + (ck & 3) * 4;
        const float dv[4] = {v.x, v.y, v.z, v.w};
        #pragma unroll
        for (int j = 0; j < 4; ++j) {
            const float d = dv[j];
            const float m = (d > thr) ? 1.0f : 0.0f;
            s_d0[p][ci + j] = d * m;
            s_m0[p][ci + j] = m;
            s_fd[p][ci + j] = (m > 0.f) ? d * (1.0f / 1.00001f) : -1.0f;
        }
    }
    __syncthreads();   // the ONLY block barrier

    const int w = t >> 6, lane = t & 63;
    const int pid = pid0 + w;
    float* fd = s_fd[w];
    float* d0 = s_d0[w];
    float* m0 = s_m0[w];
    unsigned short* Fp = (unsigned short*)(F + (size_t)pid * 672);

    // ---- g16 fill: 4 contiguous cells/lane, shared 3x6 window (R2-proven) ----
    const int row = lane >> 2, cq = lane & 3, cg = cq * 4;
    const float4* fdv = (const float4*)fd;
    for (;;) {
        float colS[6], colN[6];
        #pragma unroll
        for (int c = 0; c < 6; ++c) { colS[c] = 0.f; colN[c] = 0.f; }
        float myv[4];
        #pragma unroll
        for (int dr = 0; dr < 3; ++dr) {
            const int r = row - 1 + dr;
            if ((unsigned)r < 16u) {
                const float4 mid = fdv[r * 4 + cq];
                const float lft = (cg > 0)  ? fd[r * 16 + cg - 1] : -1.f;
                const float rgt = (cg < 12) ? fd[r * 16 + cg + 4] : -1.f;
                const float vv[6] = {lft, mid.x, mid.y, mid.z, mid.w, rgt};
                if (dr == 1) { myv[0] = mid.x; myv[1] = mid.y; myv[2] = mid.z; myv[3] = mid.w; }
                #pragma unroll
                for (int c = 0; c < 6; ++c) {
                    colS[c] += fmaxf(vv[c], 0.f);
                    colN[c] += (vv[c] >= 0.f) ? 1.f : 0.f;
                }
            }
        }
        float nv[4];
        int wmask = 0;
        #pragma unroll
        for (int j = 0; j < 4; ++j) {
            if (myv[j] < 0.f) {
                const float N = colN[j] + colN[j + 1] + colN[j + 2];
                if (N > 0.f) {
                    nv[j] = (colS[j] + colS[j + 1] + colS[j + 2]) / N;
                    wmask |= (1 << j);
                }
            }
        }
        const bool any = __any(wmask != 0);
        #pragma unroll
        for (int j = 0; j < 4; ++j)
            if (wmask & (1 << j)) fd[row * 16 + cg + j] = nv[j];
        if (!any) break;
    }
    // emit g16 dh + mask (packed 4x bf16 = 8B stores)
    {
        const int co = row * 16 + cg;
        const float4 fin = fdv[row * 4 + cq];
        ushort4 o;
        o.x = f2bf(fmaxf(fin.x, 0.f)); o.y = f2bf(fmaxf(fin.y, 0.f));
        o.z = f2bf(fmaxf(fin.z, 0.f)); o.w = f2bf(fmaxf(fin.w, 0.f));
        *(ushort4*)(Fp + co) = o;
        const float4 mm = *(const float4*)&m0[co];
        ushort4 om;
        om.x = f2bf(mm.x); om.y = f2bf(mm.y); om.z = f2bf(mm.z); om.w = f2bf(mm.w);
        *(ushort4*)(Fp + 256 + co) = om;
    }

    // ---- g8: R2 pool (LDS reads), fill in registers via UNCONDITIONAL shfl ----
    const int r8 = lane >> 3, c8 = lane & 7;
    float mp8;
    float f8v;
    {
        const int i0 = r8 * 32 + c8 * 2;
        const float num = d0[i0] + d0[i0 + 1] + d0[i0 + 16] + d0[i0 + 17];
        const float cm  = m0[i0] + m0[i0 + 1] + m0[i0 + 16] + m0[i0 + 17];
        mp8 = cm * 0.25f;
        const float dh = (num * 0.25f) / (mp8 + 1e-5f);
        f8v = (mp8 >= 1e-5f) ? dh : -1.f;
    }
    {
        const float okU = (r8 > 0) ? 1.f : 0.f;
        const float okD = (r8 < 7) ? 1.f : 0.f;
        const float okL = (c8 > 0) ? 1.f : 0.f;
        const float okR = (c8 < 7) ? 1.f : 0.f;
        for (int it = 0; it < 8; ++it) {
            const float nU  = __shfl(f8v, (lane - 8) & 63);
            const float nD  = __shfl(f8v, (lane + 8) & 63);
            const float nL  = __shfl(f8v, (lane - 1) & 63);
            const float nR  = __shfl(f8v, (lane + 1) & 63);
            const float nUL = __shfl(f8v, (lane - 9) & 63);
            const float nUR = __shfl(f8v, (lane - 7) & 63);
            const float nDL = __shfl(f8v, (lane + 7) & 63);
            const float nDR = __shfl(f8v, (lane + 9) & 63);
            const float S = okU * fmaxf(nU, 0.f) + okD * fmaxf(nD, 0.f)
                          + okL * fmaxf(nL, 0.f) + okR * fmaxf(nR, 0.f)
                          + (okU * okL) * fmaxf(nUL, 0.f) + (okU * okR) * fmaxf(nUR, 0.f)
                          + (okD * okL) * fmaxf(nDL, 0.f) + (okD * okR) * fmaxf(nDR, 0.f);
            const float N = okU * ((nU >= 0.f) ? 1.f : 0.f) + okD * ((nD >= 0.f) ? 1.f : 0.f)
                          + okL * ((nL >= 0.f) ? 1.f : 0.f) + okR * ((nR >= 0.f) ? 1.f : 0.f)
                          + (okU * okL) * ((nUL >= 0.f) ? 1.f : 0.f) + (okU * okR) * ((nUR >= 0.f) ? 1.f : 0.f)
                          + (okD * okL) * ((nDL >= 0.f) ? 1.f : 0.f) + (okD * okR) * ((nDR >= 0.f) ? 1.f : 0.f);
            asm volatile("" :: "v"(S), "v"(N));   // pin to uniform path (no sinking)
            int fill = 0; float nv = 0.f;
            if (f8v < 0.f && N > 0.f) { nv = S / N; fill = 1; }
            const bool any = __any(fill);
            if (fill) f8v = nv;
            if (!any) break;
        }
        Fp[512 + lane] = f2bf(fmaxf(f8v, 0.f));
        Fp[576 + lane] = f2bf(mp8);
    }

    // ---- g4: R2 pool at lanes<16, broadcast, fill via UNCONDITIONAL shfl ----
    float mp4 = 0.f, f4v = -1.f;
    if (lane < 16) {
        const int oh = lane >> 2, ow = lane & 3;
        float num = 0.f, cm = 0.f;
        #pragma unroll
        for (int yy = 0; yy < 4; ++yy)
            #pragma unroll
            for (int xx = 0; xx < 4; ++xx) {
                const int q = (oh * 4 + yy) * 16 + (ow * 4 + xx);
                num += d0[q]; cm += m0[q];
            }
        mp4 = cm * (1.f / 16.f);
        const float dh = (num * (1.f / 16.f)) / (mp4 + 1e-5f);
        f4v = (mp4 >= 1e-5f) ? dh : -1.f;
    }
    f4v = __shfl(f4v, lane & 15);   // mirror canonical 4x4 grid to all lanes
    {
        const int c4l = lane & 15;
        const int r4 = c4l >> 2, c4 = c4l & 3;
        const float okU = (r4 > 0) ? 1.f : 0.f;
        const float okD = (r4 < 3) ? 1.f : 0.f;
        const float okL = (c4 > 0) ? 1.f : 0.f;
        const float okR = (c4 < 3) ? 1.f : 0.f;
        for (int it = 0; it < 4; ++it) {
            const float nU  = __shfl(f4v, (c4l - 4) & 63);
            const float nD  = __shfl(f4v, (c4l + 4) & 63);
            const float nL  = __shfl(f4v, (c4l - 1) & 63);
            const float nR  = __shfl(f4v, (c4l + 1) & 63);
            const float nUL = __shfl(f4v, (c4l - 5) & 63);
            const float nUR = __shfl(f4v, (c4l - 3) & 63);
            const float nDL = __shfl(f4v, (c4l + 3) & 63);
            const float nDR = __shfl(f4v, (c4l + 5) & 63);
            const float S = okU * fmaxf(nU, 0.f) + okD * fmaxf(nD, 0.f)
                          + okL * fmaxf(nL, 0.f) + okR * fmaxf(nR, 0.f)
                          + (okU * okL) * fmaxf(nUL, 0.f) + (okU * okR) * fmaxf(nUR, 0.f)
                          + (okD * okL) * fmaxf(nDL, 0.f) + (okD * okR) * fmaxf(nDR, 0.f);
            const float N = okU * ((nU >= 0.f) ? 1.f : 0.f) + okD * ((nD >= 0.f) ? 1.f : 0.f)
                          + okL * ((nL >= 0.f) ? 1.f : 0.f) + okR * ((nR >= 0.f) ? 1.f : 0.f)
                          + (okU * okL) * ((nUL >= 0.f) ? 1.f : 0.f) + (okU * okR) * ((nUR >= 0.f) ? 1.f : 0.f)
                          + (okD * okL) * ((nDL >= 0.f) ? 1.f : 0.f) + (okD * okR) * ((nDR >= 0.f) ? 1.f : 0.f);
            asm volatile("" :: "v"(S), "v"(N));   // pin to uniform path (no sinking)
            int fill = 0; float nv = 0.f;
            if (f4v < 0.f && N > 0.f) { nv = S / N; fill = 1; }
            const bool any = __any(fill);
            if (fill) f4v = nv;
            if (!any) break;
        }
        if (lane < 16) {
            Fp[640 + lane] = f2bf(fmaxf(f4v, 0.f));
            Fp[656 + lane] = f2bf(mp4);
        }
        const unsigned long long bal = __ballot(lane < 16 && mp4 > 0.f);
        if (lane == 0) maskout[pid] = bal ? 1.0f : 0.0f;
    }
}

// -------- GEMM: out[32768][768] = F[32768][672] @ W2[768][672]^T + biasT --------
// 128x128 tile, BK=96 (7 K-steps, 48 MFMA per barrier pair), XCD swizzle.
// LDS tiles [kcc(12)][row(128)][8] bf16 -> frag reads contiguous 16B/lane.
__global__ __launch_bounds__(256) void gemm_kernel(const short* __restrict__ F,
                                                   const short* __restrict__ W2,
                                                   const float* __restrict__ biasT,
                                                   float* __restrict__ out) {
    constexpr int K = 672, N = 768;
    const int bid = blockIdx.x;                    // 1536 = 256 m-tiles x 6 n-tiles
    const int swz = (bid & 7) * 192 + (bid >> 3);  // bijective XCD swizzle (1536 % 8 == 0)
    const int tm = swz / 6, tn = swz % 6;
    const int m0 = tm * 128, e0 = tn * 128;
    const int t = threadIdx.x;
    const int wave = t >> 6, lane = t & 63;
    const int wm = wave >> 1, wn = wave & 1;
    const int lg = lane & 15, kc = lane >> 4;

    __shared__ short lds_a[12288];   // [12][128][8]
    __shared__ short lds_b[12288];

    f32x4 acc[4][4];
    const f32x4 zero = {0.f, 0.f, 0.f, 0.f};
    #pragma unroll
    for (int i = 0; i < 4; ++i)
        #pragma unroll
        for (int j = 0; j < 4; ++j) acc[i][j] = zero;

    for (int kb = 0; kb < K; kb += 96) {
        __syncthreads();   // previous iter's reads done before overwrite
        #pragma unroll
        for (int c = 0; c < 6; ++c) {
            const int s = wave * 6 + c;            // 24 slots of 1KB each
            const int kcc = s >> 1, hf = s & 1;
            const int row0 = hf * 64;
            async_copy16(F  + (size_t)(m0 + row0 + lane) * K + kb + kcc * 8,
                         &lds_a[(kcc * 128 + row0) * 8]);
            async_copy16(W2 + (size_t)(e0 + row0 + lane) * K + kb + kcc * 8,
                         &lds_b[(kcc * 128 + row0) * 8]);
        }
        __syncthreads();   // vmcnt(0) drain + barrier: staged data visible

        #pragma unroll
        for (int ks = 0; ks < 3; ++ks) {
            bf16x8 af[4], bfr[4];
            const int kco = (ks * 4 + kc) * 128;
            #pragma unroll
            for (int i = 0; i < 4; ++i) {
                af[i]  = *(const bf16x8*)&lds_a[(kco + wm * 64 + i * 16 + lg) * 8];
                bfr[i] = *(const bf16x8*)&lds_b[(kco + wn * 64 + i * 16 + lg) * 8];
            }
            #pragma unroll
            for (int i = 0; i < 4; ++i)
                #pragma unroll
                for (int j = 0; j < 4; ++j)
                    acc[i][j] = __builtin_amdgcn_mfma_f32_16x16x32_bf16(af[i], bfr[j], acc[i][j], 0, 0, 0);
        }
    }

    // epilogue: C/D layout col=lane&15, row=(lane>>4)*4+reg (m89-verified)
    const int rbase = (lane >> 4) * 4;
    #pragma unroll
    for (int j = 0; j < 4; ++j) {
        const int e = e0 + wn * 64 + j * 16 + lg;
        const float bs = biasT[e];
        #pragma unroll
        for (int i = 0; i < 4; ++i) {
            const int mr = m0 + wm * 64 + i * 16 + rbase;
            #pragma unroll
            for (int r = 0; r < 4; ++r)
                out[(size_t)(mr + r) * N + e] = acc[i][j][r] + bs;
        }
    }
}

extern "C" void kernel_launch(void* const* d_in, const int* in_sizes, int n_in,
                              void* d_out, int out_size, void* d_ws, size_t ws_size,
                              hipStream_t stream) {
    const float* x  = (const float*)d_in[0];
    const float* w0 = (const float*)d_in[1];
    const float* b0 = (const float*)d_in[2];
    const float* w1 = (const float*)d_in[3];
    const float* b1 = (const float*)d_in[4];
    const float* w2 = (const float*)d_in[5];
    const float* b2 = (const float*)d_in[6];
    float* out = (float*)d_out;

    char* ws = (char*)d_ws;
    __hip_bfloat16* F   = (__hip_bfloat16*)ws;
    __hip_bfloat16* W2  = (__hip_bfloat16*)(ws + 44040192);
    float* biasT        = (float*)(ws + 45072384);
    float* partial      = (float*)(ws + 45075456);
    float* dmin         = (float*)(ws + 45077504);
    float* maskout      = out + 25165824;   // feat is 32*1024*768

    min_partial_kernel<<<512, 256, 0, stream>>>(x, partial);
    min_final_kernel<<<1, 64, 0, stream>>>(partial, dmin);
    prep_kernel<<<2016, 256, 0, stream>>>(w0, b0, w1, b1, w2, b2, W2, biasT);
    patch_kernel<<<8192, 256, 0, stream>>>(x, dmin, F, maskout);
    gemm_kernel<<<1536, 256, 0, stream>>>((const short*)F, (const short*)W2, biasT, out);
}

// Round 6
// 131.434 us; speedup vs baseline: 1.4804x; 1.4804x over previous
//
#include <hip/hip_runtime.h>
#include <hip/hip_bf16.h>

typedef __attribute__((ext_vector_type(8))) short bf16x8;
typedef __attribute__((ext_vector_type(4))) float f32x4;

// ---------------- ws layout ----------------
// F    : bf16 [32768][672]            @ 0          (44,040,192 B)
// W2   : bf16 [768][672]              @ 44,040,192 (1,032,192 B)
// biasT: f32  [768]                   @ 45,072,384 (3,072 B)
// part : f32  [512]                   @ 45,075,456 (2,048 B)
// dmin : f32  [32]                    @ 45,077,504 (128 B)

__device__ __forceinline__ void async_copy16(const void* gsrc, void* ldst) {
    __builtin_amdgcn_global_load_lds(
        (const __attribute__((address_space(1))) void*)gsrc,
        (__attribute__((address_space(3))) void*)ldst,
        16, 0, 0);
}

__device__ __forceinline__ unsigned short f2bf(float f) {  // RNE, matches __float2bfloat16
    unsigned u = __float_as_uint(f);
    u += 0x7FFFu + ((u >> 16) & 1u);
    return (unsigned short)(u >> 16);
}

// -------- per-batch min (two stage) --------
__global__ __launch_bounds__(256) void min_partial_kernel(const float* __restrict__ x,
                                                          float* __restrict__ partial) {
    const int blk = blockIdx.x;           // 512 blocks: 32 batches x 16 chunks
    const int b = blk >> 4, c = blk & 15;
    const float4* p = (const float4*)(x + (size_t)b * 262144 + (size_t)c * 16384);
    float mn = 3.0e38f;
    for (int i = threadIdx.x; i < 4096; i += 256) {
        float4 v = p[i];
        mn = fminf(mn, fminf(fminf(v.x, v.y), fminf(v.z, v.w)));
    }
    #pragma unroll
    for (int off = 32; off > 0; off >>= 1)
        mn = fminf(mn, __shfl_down(mn, off));
    __shared__ float red[4];
    if ((threadIdx.x & 63) == 0) red[threadIdx.x >> 6] = mn;
    __syncthreads();
    if (threadIdx.x == 0)
        partial[blk] = fminf(fminf(red[0], red[1]), fminf(red[2], red[3]));
}

__global__ void min_final_kernel(const float* __restrict__ partial, float* __restrict__ dmin) {
    const int t = threadIdx.x;
    if (t < 32) {
        float mn = 3.0e38f;
        for (int i = 0; i < 16; ++i) mn = fminf(mn, partial[t * 16 + i]);
        dmin[t] = mn;
    }
}

// -------- weight repack: W2[e][k] bf16, k = [g16 dh|g16 mp|g8 dh|g8 mp|g4 dh|g4 mp] --------
__global__ __launch_bounds__(256) void prep_kernel(const float* __restrict__ w0, const float* __restrict__ b0,
                                                   const float* __restrict__ w1, const float* __restrict__ b1,
                                                   const float* __restrict__ w2, const float* __restrict__ b2,
                                                   __hip_bfloat16* __restrict__ W2, float* __restrict__ biasT) {
    const int idx = blockIdx.x * 256 + threadIdx.x;
    if (idx < 768 * 672) {
        const int e = idx / 672, k = idx - e * 672;
        float v;
        if (k < 512)      v = w0[e * 512 + k];          // (2,16,16) flat
        else if (k < 640) v = w1[e * 128 + (k - 512)];  // (2,8,8) flat
        else              v = w2[e * 32  + (k - 640)];  // (2,4,4) flat
        W2[idx] = __float2bfloat16(v);
    }
    if (idx < 768) biasT[idx] = b0[idx] + b1[idx] + b2[idx];
}

// -------- per-patch: PURE REGISTER, one wave per patch, zero LDS --------
// Encoding: valid cell -> 256 + dh (dh in [0,1)); invalid/out-of-bounds -> 0.
// Window sum w: N = floor(w/256) valid neighbors, S = w - 256N value sum.
// ALL __shfl are unconditional (masked index) with multiplicative 0/1 masks
// applied AFTER the shuffle; asm-pins keep them on the uniform path
// (EXEC-masked ds_bpermute reads inactive lanes -> undefined; R3/R4 bug).
__global__ __launch_bounds__(256) void patch_kernel(const float* __restrict__ x,
                                                    const float* __restrict__ dmin,
                                                    __hip_bfloat16* __restrict__ F,
                                                    float* __restrict__ maskout) {
    const int t = threadIdx.x;
    const int w = t >> 6, lane = t & 63;
    const int pid = blockIdx.x * 4 + w;       // wave = patch
    const int b = pid >> 10, n = pid & 1023;
    const int gi = n >> 5, gj = n & 31;
    const int row = lane >> 2, cq = lane & 3, cg = cq * 4;
    const float thr = dmin[b] + 1e-6f;

    const float4 v = *(const float4*)(x + ((size_t)(b * 512 + gi * 16 + row)) * 512 + gj * 16 + cg);
    float enc0, enc1, enc2, enc3;
    ushort4 om;
    {
        const bool v0 = v.x > thr, v1 = v.y > thr, v2 = v.z > thr, v3 = v.w > thr;
        enc0 = v0 ? fmaf(v.x, 0.99999000009999f, 256.0f) : 0.0f;   // 256 + d/1.00001
        enc1 = v1 ? fmaf(v.y, 0.99999000009999f, 256.0f) : 0.0f;
        enc2 = v2 ? fmaf(v.z, 0.99999000009999f, 256.0f) : 0.0f;
        enc3 = v3 ? fmaf(v.w, 0.99999000009999f, 256.0f) : 0.0f;
        om.x = v0 ? 0x3F80 : 0; om.y = v1 ? 0x3F80 : 0;            // bf16(1.0/0.0)
        om.z = v2 ? 0x3F80 : 0; om.w = v3 ? 0x3F80 : 0;
    }

    // ---- pools from initial encoded values (register butterflies) ----
    const float vs0 = enc0 + __shfl(enc0, lane ^ 4);   // vertical row-pair sums
    const float vs1 = enc1 + __shfl(enc1, lane ^ 4);
    const float vs2 = enc2 + __shfl(enc2, lane ^ 4);
    const float vs3 = enc3 + __shfl(enc3, lane ^ 4);
    const float a80 = vs0 + vs1, a81 = vs2 + vs3;      // g8 cells (row>>1,2cq),(row>>1,2cq+1)
    const int r8 = lane >> 3, c8 = lane & 7;
    const int src8 = r8 * 8 + (c8 >> 1);
    const float t80 = __shfl(a80, src8), t81 = __shfl(a81, src8);
    const float sum8 = (c8 & 1) ? t81 : t80;           // encoded 2x2 sum of my g8 cell
    const float N8 = floorf(sum8 * 0.00390625f);
    const float S8 = fmaf(N8, -256.0f, sum8);
    const float mp8 = N8 * 0.25f;
    const float dh8 = (S8 * 0.2500025f) / fmaf(N8, 0.25f, 1e-5f);  // (S/1.00001/4)/(mp8+1e-5)
    float f8v = (N8 >= 1.0f) ? fmaxf(dh8, 0.0f) : -1.0f;
    // g4 sums from g8 sums
    const float vp8 = sum8 + __shfl(sum8, lane ^ 8);
    const float sum4w = vp8 + __shfl(vp8, lane ^ 1);   // g4 cell (r8>>1,c8>>1), duplicated
    const int cell4 = lane & 15;
    const int r4 = cell4 >> 2, c4 = cell4 & 3;
    const float s4 = __shfl(sum4w, r4 * 16 + c4 * 2);
    const float N4 = floorf(s4 * 0.00390625f);
    const float S4 = fmaf(N4, -256.0f, s4);
    const float mp4 = N4 * 0.0625f;
    const float dh4 = (S4 * 0.062500625f) / fmaf(N4, 0.0625f, 1e-5f);
    float f4v = (N4 >= 1.0f) ? fmaxf(dh4, 0.0f) : -1.0f;

    // ---- g16 fill: 4 contiguous cells/lane, 14 shfls/iter, encode arithmetic ----
    {
        const float okT = (row > 0) ? 1.f : 0.f, okB = (row < 15) ? 1.f : 0.f;
        const float okL = (cq > 0) ? 1.f : 0.f, okR = (cq < 3) ? 1.f : 0.f;
        const float okTL = okT * okL, okTR = okT * okR, okBL = okB * okL, okBR = okB * okR;
        const int liU = (lane - 4) & 63, liD = (lane + 4) & 63;
        const int liL = (lane - 1) & 63, liR = (lane + 1) & 63;
        const int liUL = (lane - 5) & 63, liUR = (lane - 3) & 63;
        const int liDL = (lane + 3) & 63, liDR = (lane + 5) & 63;
        for (;;) {
            float u0 = __shfl(enc0, liU), u1 = __shfl(enc1, liU);
            float u2 = __shfl(enc2, liU), u3 = __shfl(enc3, liU);
            float b0_ = __shfl(enc0, liD), b1_ = __shfl(enc1, liD);
            float b2_ = __shfl(enc2, liD), b3_ = __shfl(enc3, liD);
            float eL  = __shfl(enc3, liL)  * okL;
            float eR  = __shfl(enc0, liR)  * okR;
            float eUL = __shfl(enc3, liUL) * okTL;
            float eUR = __shfl(enc0, liUR) * okTR;
            float eDL = __shfl(enc3, liDL) * okBL;
            float eDR = __shfl(enc0, liDR) * okBR;
            u0 *= okT; u1 *= okT; u2 *= okT; u3 *= okT;
            b0_ *= okB; b1_ *= okB; b2_ *= okB; b3_ *= okB;
            const float c0 = eUL + eL + eDL;
            const float c1 = u0 + enc0 + b0_;
            const float c2 = u1 + enc1 + b1_;
            const float c3 = u2 + enc2 + b2_;
            const float c4_ = u3 + enc3 + b3_;
            const float c5 = eUR + eR + eDR;
            float w0s = c0 + c1 + c2, w1s = c1 + c2 + c3;
            float w2s = c2 + c3 + c4_, w3s = c3 + c4_ + c5;
            asm volatile("" :: "v"(w0s), "v"(w1s), "v"(w2s), "v"(w3s));  // pin (uniform path)
            int fill = 0;
            if (enc0 < 256.f) {
                const float Nf = floorf(w0s * 0.00390625f);
                if (Nf >= 1.f) { enc0 = 256.f + fmaxf(fmaf(Nf, -256.f, w0s), 0.f) * __builtin_amdgcn_rcpf(Nf); fill = 1; }
            }
            if (enc1 < 256.f) {
                const float Nf = floorf(w1s * 0.00390625f);
                if (Nf >= 1.f) { enc1 = 256.f + fmaxf(fmaf(Nf, -256.f, w1s), 0.f) * __builtin_amdgcn_rcpf(Nf); fill = 1; }
            }
            if (enc2 < 256.f) {
                const float Nf = floorf(w2s * 0.00390625f);
                if (Nf >= 1.f) { enc2 = 256.f + fmaxf(fmaf(Nf, -256.f, w2s), 0.f) * __builtin_amdgcn_rcpf(Nf); fill = 1; }
            }
            if (enc3 < 256.f) {
                const float Nf = floorf(w3s * 0.00390625f);
                if (Nf >= 1.f) { enc3 = 256.f + fmaxf(fmaf(Nf, -256.f, w3s), 0.f) * __builtin_amdgcn_rcpf(Nf); fill = 1; }
            }
            if (!__any(fill)) break;
        }
    }
    unsigned short* Fp = (unsigned short*)(F + (size_t)pid * 672);
    {
        ushort4 o;
        o.x = f2bf(fmaxf(enc0 - 256.f, 0.f)); o.y = f2bf(fmaxf(enc1 - 256.f, 0.f));
        o.z = f2bf(fmaxf(enc2 - 256.f, 0.f)); o.w = f2bf(fmaxf(enc3 - 256.f, 0.f));
        const int co = row * 16 + cg;
        *(ushort4*)(Fp + co) = o;
        *(ushort4*)(Fp + 256 + co) = om;
    }

    // ---- g8 fill (R5-proven: unconditional shfl + post-masks) ----
    {
        const float okU = (r8 > 0) ? 1.f : 0.f;
        const float okD = (r8 < 7) ? 1.f : 0.f;
        const float okL = (c8 > 0) ? 1.f : 0.f;
        const float okR = (c8 < 7) ? 1.f : 0.f;
        for (int it = 0; it < 8; ++it) {
            const float nU  = __shfl(f8v, (lane - 8) & 63);
            const float nD  = __shfl(f8v, (lane + 8) & 63);
            const float nL  = __shfl(f8v, (lane - 1) & 63);
            const float nR  = __shfl(f8v, (lane + 1) & 63);
            const float nUL = __shfl(f8v, (lane - 9) & 63);
            const float nUR = __shfl(f8v, (lane - 7) & 63);
            const float nDL = __shfl(f8v, (lane + 7) & 63);
            const float nDR = __shfl(f8v, (lane + 9) & 63);
            const float S = okU * fmaxf(nU, 0.f) + okD * fmaxf(nD, 0.f)
                          + okL * fmaxf(nL, 0.f) + okR * fmaxf(nR, 0.f)
                          + (okU * okL) * fmaxf(nUL, 0.f) + (okU * okR) * fmaxf(nUR, 0.f)
                          + (okD * okL) * fmaxf(nDL, 0.f) + (okD * okR) * fmaxf(nDR, 0.f);
            const float N = okU * ((nU >= 0.f) ? 1.f : 0.f) + okD * ((nD >= 0.f) ? 1.f : 0.f)
                          + okL * ((nL >= 0.f) ? 1.f : 0.f) + okR * ((nR >= 0.f) ? 1.f : 0.f)
                          + (okU * okL) * ((nUL >= 0.f) ? 1.f : 0.f) + (okU * okR) * ((nUR >= 0.f) ? 1.f : 0.f)
                          + (okD * okL) * ((nDL >= 0.f) ? 1.f : 0.f) + (okD * okR) * ((nDR >= 0.f) ? 1.f : 0.f);
            asm volatile("" :: "v"(S), "v"(N));   // pin to uniform path
            int fill = 0; float nv = 0.f;
            if (f8v < 0.f && N > 0.f) { nv = S / N; fill = 1; }
            const bool any = __any(fill);
            if (fill) f8v = nv;
            if (!any) break;
        }
        Fp[512 + lane] = f2bf(fmaxf(f8v, 0.f));
        Fp[576 + lane] = f2bf(mp8);
    }

    // ---- g4 fill (R5-proven; 4x4 mirrored across lane groups) ----
    {
        const float okU = (r4 > 0) ? 1.f : 0.f;
        const float okD = (r4 < 3) ? 1.f : 0.f;
        const float okL = (c4 > 0) ? 1.f : 0.f;
        const float okR = (c4 < 3) ? 1.f : 0.f;
        for (int it = 0; it < 4; ++it) {
            const float nU  = __shfl(f4v, (cell4 - 4) & 63);
            const float nD  = __shfl(f4v, (cell4 + 4) & 63);
            const float nL  = __shfl(f4v, (cell4 - 1) & 63);
            const float nR  = __shfl(f4v, (cell4 + 1) & 63);
            const float nUL = __shfl(f4v, (cell4 - 5) & 63);
            const float nUR = __shfl(f4v, (cell4 - 3) & 63);
            const float nDL = __shfl(f4v, (cell4 + 3) & 63);
            const float nDR = __shfl(f4v, (cell4 + 5) & 63);
            const float S = okU * fmaxf(nU, 0.f) + okD * fmaxf(nD, 0.f)
                          + okL * fmaxf(nL, 0.f) + okR * fmaxf(nR, 0.f)
                          + (okU * okL) * fmaxf(nUL, 0.f) + (okU * okR) * fmaxf(nUR, 0.f)
                          + (okD * okL) * fmaxf(nDL, 0.f) + (okD * okR) * fmaxf(nDR, 0.f);
            const float N = okU * ((nU >= 0.f) ? 1.f : 0.f) + okD * ((nD >= 0.f) ? 1.f : 0.f)
                          + okL * ((nL >= 0.f) ? 1.f : 0.f) + okR * ((nR >= 0.f) ? 1.f : 0.f)
                          + (okU * okL) * ((nUL >= 0.f) ? 1.f : 0.f) + (okU * okR) * ((nUR >= 0.f) ? 1.f : 0.f)
                          + (okD * okL) * ((nDL >= 0.f) ? 1.f : 0.f) + (okD * okR) * ((nDR >= 0.f) ? 1.f : 0.f);
            asm volatile("" :: "v"(S), "v"(N));   // pin to uniform path
            int fill = 0; float nv = 0.f;
            if (f4v < 0.f && N > 0.f) { nv = S / N; fill = 1; }
            const bool any = __any(fill);
            if (fill) f4v = nv;
            if (!any) break;
        }
        if (lane < 16) {
            Fp[640 + lane] = f2bf(fmaxf(f4v, 0.f));
            Fp[656 + lane] = f2bf(mp4);
        }
        const unsigned long long bal = __ballot(lane < 16 && N4 >= 1.0f);
        if (lane == 0) maskout[pid] = bal ? 1.0f : 0.0f;
    }
}

// -------- GEMM: out[32768][768] = F[32768][672] @ W2[768][672]^T + biasT --------
// R2-proven structure: 128x128 tile, BK=32 (8 KB LDS), + bijective XCD swizzle
// (colocates the 6 same-tm tiles on one XCD -> 6x F L2 reuse).
__global__ __launch_bounds__(256) void gemm_kernel(const short* __restrict__ F,
                                                   const short* __restrict__ W2,
                                                   const float* __restrict__ biasT,
                                                   float* __restrict__ out) {
    constexpr int K = 672, N = 768;
    const int bid = blockIdx.x;                    // 1536 = 256 m-tiles x 6 n-tiles
    const int swz = (bid & 7) * 192 + (bid >> 3);  // bijective (1536 % 8 == 0)
    const int tm = swz / 6, tn = swz % 6;
    const int m0 = tm * 128, e0 = tn * 128;
    const int t = threadIdx.x;
    const int wave = t >> 6, lane = t & 63;
    const int wm = wave >> 1, wn = wave & 1;
    const int lg = lane & 15, kc = lane >> 4;

    __shared__ short lds_a[4096];   // [4][128][8]
    __shared__ short lds_b[4096];

    f32x4 acc[4][4];
    const f32x4 zero = {0.f, 0.f, 0.f, 0.f};
    #pragma unroll
    for (int i = 0; i < 4; ++i)
        #pragma unroll
        for (int j = 0; j < 4; ++j) acc[i][j] = zero;

    for (int kb = 0; kb < K; kb += 32) {
        __syncthreads();
        #pragma unroll
        for (int si = 0; si < 2; ++si) {
            const int s = wave * 2 + si;
            const int row = ((s & 1) << 6) + lane;
            const int kcc = s >> 1;
            async_copy16(F  + (size_t)(m0 + row) * K + kb + kcc * 8, &lds_a[s * 512]);
            async_copy16(W2 + (size_t)(e0 + row) * K + kb + kcc * 8, &lds_b[s * 512]);
        }
        __syncthreads();

        bf16x8 af[4], bfr[4];
        #pragma unroll
        for (int i = 0; i < 4; ++i) {
            af[i]  = *(const bf16x8*)&lds_a[(kc * 128 + wm * 64 + i * 16 + lg) * 8];
            bfr[i] = *(const bf16x8*)&lds_b[(kc * 128 + wn * 64 + i * 16 + lg) * 8];
        }
        #pragma unroll
        for (int i = 0; i < 4; ++i)
            #pragma unroll
            for (int j = 0; j < 4; ++j)
                acc[i][j] = __builtin_amdgcn_mfma_f32_16x16x32_bf16(af[i], bfr[j], acc[i][j], 0, 0, 0);
    }

    // epilogue: C/D layout col=lane&15, row=(lane>>4)*4+reg (m89-verified)
    const int rbase = (lane >> 4) * 4;
    #pragma unroll
    for (int j = 0; j < 4; ++j) {
        const int e = e0 + wn * 64 + j * 16 + lg;
        const float bs = biasT[e];
        #pragma unroll
        for (int i = 0; i < 4; ++i) {
            const int mr = m0 + wm * 64 + i * 16 + rbase;
            #pragma unroll
            for (int r = 0; r < 4; ++r)
                out[(size_t)(mr + r) * N + e] = acc[i][j][r] + bs;
        }
    }
}

extern "C" void kernel_launch(void* const* d_in, const int* in_sizes, int n_in,
                              void* d_out, int out_size, void* d_ws, size_t ws_size,
                              hipStream_t stream) {
    const float* x  = (const float*)d_in[0];
    const float* w0 = (const float*)d_in[1];
    const float* b0 = (const float*)d_in[2];
    const float* w1 = (const float*)d_in[3];
    const float* b1 = (const float*)d_in[4];
    const float* w2 = (const float*)d_in[5];
    const float* b2 = (const float*)d_in[6];
    float* out = (float*)d_out;

    char* ws = (char*)d_ws;
    __hip_bfloat16* F   = (__hip_bfloat16*)ws;
    __hip_bfloat16* W2  = (__hip_bfloat16*)(ws + 44040192);
    float* biasT        = (float*)(ws + 45072384);
    float* partial      = (float*)(ws + 45075456);
    float* dmin         = (float*)(ws + 45077504);
    float* maskout      = out + 25165824;   // feat is 32*1024*768

    min_partial_kernel<<<512, 256, 0, stream>>>(x, partial);
    min_final_kernel<<<1, 64, 0, stream>>>(partial, dmin);
    prep_kernel<<<2016, 256, 0, stream>>>(w0, b0, w1, b1, w2, b2, W2, biasT);
    patch_kernel<<<8192, 256, 0, stream>>>(x, dmin, F, maskout);
    gemm_kernel<<<1536, 256, 0, stream>>>((const short*)F, (const short*)W2, biasT, out);
}